// Round 14
// baseline (204.877 us; speedup 1.0000x reference)
//
#include <hip/hip_runtime.h>

#define NN 100000
#define NE 1600000
#define FD 128
#define NBUK 196            // ceil(NN / 512), bucket = col >> 9
#define BCAP 9216           // fixed slots per bucket (mean 8163, +11 sigma)
#define EPBB 4096           // edges per block in k_bin
#define NBB 391             // ceil(NE / EPBB)
#define NGROUP 6250         // NN/16 row-groups for MFMA gemm
#define GEMM_BLKS 1563      // ceil(NGROUP / 4)

typedef unsigned int  u32;
typedef unsigned short u16;
typedef __bf16 bf16x8 __attribute__((ext_vector_type(8)));
typedef float  f32x4v __attribute__((ext_vector_type(4)));

__device__ __forceinline__ u16 f2bf(float f) {
    u32 u = __float_as_uint(f);
    u32 r = (u + 0x7FFFu + ((u >> 16) & 1u)) >> 16;   // RNE
    return (u16)r;
}

__device__ __forceinline__ void acc2(float& x, float& y, float wt, u32 w) {
    x += wt * __uint_as_float(w << 16);
    y += wt * __uint_as_float(w & 0xffff0000u);
}
__device__ __forceinline__ void acc8(float4& L, float4& H, float wt, uint4 u) {
    acc2(L.x, L.y, wt, u.x); acc2(L.z, L.w, wt, u.y);
    acc2(H.x, H.y, wt, u.z); acc2(H.z, H.w, wt, u.w);
}

// ============ bin edges (blocks 0..NBB-1) + init cursors/pack W (blocks NBB..) =
// B elem = W[q*32 + (l>>4)*8 + j][t*16 + (l&15)]  stored at Wf[((t*4+q)*64+l)*8+j]
__global__ __launch_bounds__(256) void k_bin(const int* __restrict__ row,
                                             const int* __restrict__ col,
                                             int* __restrict__ bcur,
                                             u32* __restrict__ ebuf,
                                             const float* __restrict__ W1,
                                             const float* __restrict__ W2,
                                             u16* __restrict__ Wf1,
                                             u16* __restrict__ Wf2) {
    __shared__ int hist[NBUK];
    const int tid = threadIdx.x;

    if (blockIdx.x >= NBB) {
        // ---- aux blocks: weight pack (8 blocks) ----
        int t2 = (blockIdx.x - NBB) * 256 + tid;   // 0..2047
        if (t2 >= 2048) return;
        int l = t2 & 63;
        int tq = t2 >> 6;
        int q = tq & 3, t = tq >> 2;
        int n = t * 16 + (l & 15);
        int k0 = q * 32 + (l >> 4) * 8;
        u32 p[4], r[4];
        for (int jj = 0; jj < 4; ++jj) {
            u16 lo1 = f2bf(W1[(size_t)(k0 + 2 * jj) * FD + n]);
            u16 hi1 = f2bf(W1[(size_t)(k0 + 2 * jj + 1) * FD + n]);
            p[jj] = (u32)lo1 | ((u32)hi1 << 16);
            u16 lo2 = f2bf(W2[(size_t)(k0 + 2 * jj) * FD + n]);
            u16 hi2 = f2bf(W2[(size_t)(k0 + 2 * jj + 1) * FD + n]);
            r[jj] = (u32)lo2 | ((u32)hi2 << 16);
        }
        *(uint4*)&Wf1[(size_t)t2 * 8] = make_uint4(p[0], p[1], p[2], p[3]);
        *(uint4*)&Wf2[(size_t)t2 * 8] = make_uint4(r[0], r[1], r[2], r[3]);
        return;
    }

    for (int i = tid; i < NBUK; i += 256) hist[i] = 0;
    __syncthreads();
    const int e0 = blockIdx.x * EPBB;
    const int e1 = min(e0 + EPBB, NE);
    for (int e = e0 + tid; e < e1; e += 256)
        atomicAdd(&hist[col[e] >> 9], 1);
    __syncthreads();
    for (int i = tid; i < NBUK; i += 256) {
        int c = hist[i];
        hist[i] = c ? atomicAdd(&bcur[i], c) : 0;
    }
    __syncthreads();
    for (int e = e0 + tid; e < e1; e += 256) {
        int c = col[e];
        int pos = atomicAdd(&hist[c >> 9], 1);
        ebuf[pos] = ((u32)row[e] << 9) | (u32)(c & 511);
    }
}

__global__ void k_binit(int* __restrict__ bcur) {
    int i = threadIdx.x;
    if (i < NBUK) bcur[i] = i * BCAP;
}

// ============ mega2: blocks [0,NBUK) bucket-sort; blocks [NBUK,..) GEMM-1 ======
__global__ __launch_bounds__(256, 4) void k_mega2(const u32* __restrict__ ebuf,
                                                  const int* __restrict__ bcur,
                                                  int* __restrict__ nstart,
                                                  int* __restrict__ ndeg,
                                                  float* __restrict__ dis,
                                                  int* __restrict__ srcs,
                                                  const float* __restrict__ x,
                                                  const u16* __restrict__ Wf1,
                                                  u16* __restrict__ hb) {
    __shared__ u16 smem[16384];     // 32 KB union: bucket uses 3 KB; gemm uses all
    const int tid = threadIdx.x;

    if (blockIdx.x < NBUK) {
        // ---- per-bucket counting sort -> CSC ----
        int* lcnt = (int*)smem;             // 512 ints
        int* s = lcnt + 512;                // 256 ints
        const int b = blockIdx.x;
        const int base = b * BCAP;
        const int end = bcur[b];            // base + actual count

        lcnt[tid] = 0; lcnt[tid + 256] = 0;
        __syncthreads();
        for (int i = base + tid; i < end; i += 256)
            atomicAdd(&lcnt[ebuf[i] & 511], 1);
        __syncthreads();

        const int c0 = lcnt[tid * 2], c1 = lcnt[tid * 2 + 1];
        s[tid] = c0 + c1;
        __syncthreads();
        for (int off = 1; off < 256; off <<= 1) {
            int t = 0;
            if (tid >= off) t = s[tid - off];
            __syncthreads();
            if (tid >= off) s[tid] += t;
            __syncthreads();
        }
        const int excl = (tid == 0) ? 0 : s[tid - 1];
        __syncthreads();
        lcnt[tid * 2] = excl;
        lcnt[tid * 2 + 1] = excl + c0;

        const int v0 = b * 512 + tid * 2;
        if (v0 < NN) {
            nstart[v0] = base + excl;
            ndeg[v0] = c0;
            dis[v0] = rsqrtf((float)c0 + 1.0f);
        }
        if (v0 + 1 < NN) {
            nstart[v0 + 1] = base + excl + c0;
            ndeg[v0 + 1] = c1;
            dis[v0 + 1] = rsqrtf((float)c1 + 1.0f);
        }
        __syncthreads();

        for (int i = base + tid; i < end; i += 256) {
            u32 p = ebuf[i];
            int pos = atomicAdd(&lcnt[p & 511], 1);
            srcs[base + pos] = (int)(p >> 9);
        }
        return;
    }

    // ---- GEMM-1: hb[r][f] = bf16( sum_k bf16(x[r][k]) * W1[k][f] ) ----
    {
        const uint4* s4 = (const uint4*)Wf1;
        uint4* d = (uint4*)smem;
#pragma unroll
        for (int i = 0; i < 8; ++i) d[tid + 256 * i] = s4[tid + 256 * i];
    }
    __syncthreads();

    const int wave = tid >> 6, lane = tid & 63;
    const int gid = (blockIdx.x - NBUK) * 4 + wave;
    if (gid >= NGROUP) return;
    const int row0 = gid * 16;
    const int lr = lane & 15;
    const int lh = lane >> 4;

    f32x4v acc[8];
#pragma unroll
    for (int t = 0; t < 8; ++t) { f32x4v z = {0.f, 0.f, 0.f, 0.f}; acc[t] = z; }

#pragma unroll
    for (int q = 0; q < 4; ++q) {
        const float* arow = x + (size_t)(row0 + lr) * FD + lh * 8 + q * 32;
        float4 f0 = *(const float4*)(arow);
        float4 f1 = *(const float4*)(arow + 4);
        union { bf16x8 v; u16 s[8]; } ua;
        ua.s[0] = f2bf(f0.x); ua.s[1] = f2bf(f0.y);
        ua.s[2] = f2bf(f0.z); ua.s[3] = f2bf(f0.w);
        ua.s[4] = f2bf(f1.x); ua.s[5] = f2bf(f1.y);
        ua.s[6] = f2bf(f1.z); ua.s[7] = f2bf(f1.w);
        bf16x8 a = ua.v;
#pragma unroll
        for (int t = 0; t < 8; ++t) {
            bf16x8 bfr = *(const bf16x8*)(&smem[(size_t)(t * 4 + q) * 512 + lane * 8]);
            acc[t] = __builtin_amdgcn_mfma_f32_16x16x32_bf16(a, bfr, acc[t], 0, 0, 0);
        }
    }
#pragma unroll
    for (int t = 0; t < 8; ++t) {
#pragma unroll
        for (int j = 0; j < 4; ++j) {
            const int r = row0 + lh * 4 + j;
            hb[(size_t)r * FD + t * 16 + lr] = f2bf(acc[t][j]);
        }
    }
}

// 8-deep gather core: acc over [e, end) with max MLP
__device__ __forceinline__ void gather_loop(const uint4* __restrict__ h4,
                                            const float* __restrict__ dis,
                                            const int* __restrict__ srcs,
                                            int e, int end, int f8, float dv,
                                            float4& aL, float4& aH) {
    for (; e + 7 < end; e += 8) {
        int sv[8];
#pragma unroll
        for (int i = 0; i < 8; ++i) sv[i] = srcs[e + i];
        uint4 uv[8];
#pragma unroll
        for (int i = 0; i < 8; ++i) uv[i] = h4[(size_t)sv[i] * 16 + f8];
        float wv[8];
#pragma unroll
        for (int i = 0; i < 8; ++i) wv[i] = dv * dis[sv[i]];
#pragma unroll
        for (int i = 0; i < 8; ++i) acc8(aL, aH, wv[i], uv[i]);
    }
    for (; e + 3 < end; e += 4) {
        const int s0 = srcs[e], s1 = srcs[e + 1], s2 = srcs[e + 2], s3 = srcs[e + 3];
        const float w0 = dv * dis[s0];
        const float w1 = dv * dis[s1];
        const float w2 = dv * dis[s2];
        const float w3 = dv * dis[s3];
        const uint4 u0 = h4[(size_t)s0 * 16 + f8];
        const uint4 u1 = h4[(size_t)s1 * 16 + f8];
        const uint4 u2 = h4[(size_t)s2 * 16 + f8];
        const uint4 u3 = h4[(size_t)s3 * 16 + f8];
        acc8(aL, aH, w0, u0); acc8(aL, aH, w1, u1);
        acc8(aL, aH, w2, u2); acc8(aL, aH, w3, u3);
    }
    for (; e < end; ++e) {
        const int s0 = srcs[e];
        const float w0 = dv * dis[s0];
        const uint4 u0 = h4[(size_t)s0 * 16 + f8];
        acc8(aL, aH, w0, u0);
    }
}

// ============ fused: gather-1 + bias + ReLU + GEMM-2 -> hb2 (bf16) =============
__global__ __launch_bounds__(256) void k_agg2(const u16* __restrict__ hb,
                                              const float* __restrict__ b1,
                                              const float* __restrict__ dis,
                                              const int* __restrict__ nstart,
                                              const int* __restrict__ ndeg,
                                              const int* __restrict__ srcs,
                                              const u16* __restrict__ Wf2,
                                              u16* __restrict__ hb2) {
    __shared__ u16 tile[16 * 136];      // 4352 B
    const int tid = threadIdx.x;
    const int nl = tid >> 4;            // node-local 0..15
    const int f8 = tid & 15;            // 8-feature slice
    const int v = blockIdx.x * 16 + nl; // always < NN (6250*16 = NN)
    const uint4* h4 = (const uint4*)hb;

    const float dv = dis[v];
    float4 aL = ((const float4*)b1)[f8 * 2];
    float4 aH = ((const float4*)b1)[f8 * 2 + 1];
    {
        const float sl = dv * dv;
        uint4 u = h4[(size_t)v * 16 + f8];
        acc8(aL, aH, sl, u);
    }

    const int e0 = nstart[v];
    gather_loop(h4, dis, srcs, e0, e0 + ndeg[v], f8, dv, aL, aH);

    // ReLU + bf16 pack -> LDS tile
    {
        uint4 p;
        p.x = (u32)f2bf(fmaxf(aL.x, 0.f)) | ((u32)f2bf(fmaxf(aL.y, 0.f)) << 16);
        p.y = (u32)f2bf(fmaxf(aL.z, 0.f)) | ((u32)f2bf(fmaxf(aL.w, 0.f)) << 16);
        p.z = (u32)f2bf(fmaxf(aH.x, 0.f)) | ((u32)f2bf(fmaxf(aH.y, 0.f)) << 16);
        p.w = (u32)f2bf(fmaxf(aH.z, 0.f)) | ((u32)f2bf(fmaxf(aH.w, 0.f)) << 16);
        *(uint4*)&tile[nl * 136 + f8 * 8] = p;
    }
    __syncthreads();

    // GEMM-2 on the 16-row tile: wave w owns n-tiles 2w, 2w+1
    const int wave = tid >> 6, lane = tid & 63;
    const int lr = lane & 15;
    const int lh = lane >> 4;
    f32x4v a0 = {0.f, 0.f, 0.f, 0.f}, a1 = {0.f, 0.f, 0.f, 0.f};
#pragma unroll
    for (int q = 0; q < 4; ++q) {
        bf16x8 a = *(const bf16x8*)&tile[lr * 136 + q * 32 + lh * 8];
        bf16x8 bb0 = *(const bf16x8*)&Wf2[(size_t)((2 * wave) * 4 + q) * 512 + lane * 8];
        bf16x8 bb1 = *(const bf16x8*)&Wf2[(size_t)((2 * wave + 1) * 4 + q) * 512 + lane * 8];
        a0 = __builtin_amdgcn_mfma_f32_16x16x32_bf16(a, bb0, a0, 0, 0, 0);
        a1 = __builtin_amdgcn_mfma_f32_16x16x32_bf16(a, bb1, a1, 0, 0, 0);
    }
    const int row0 = blockIdx.x * 16;
#pragma unroll
    for (int j = 0; j < 4; ++j) {
        const int r = row0 + lh * 4 + j;
        hb2[(size_t)r * FD + (2 * wave) * 16 + lr] = f2bf(a0[j]);
        hb2[(size_t)r * FD + (2 * wave + 1) * 16 + lr] = f2bf(a1[j]);
    }
}

// ============ gather-2: out f32 = b2 + dv^2*h2[v] + sum w*h2[src] ==============
__global__ __launch_bounds__(256) void k_agg_f32(const u16* __restrict__ hb,
                                                 const float* __restrict__ b,
                                                 const float* __restrict__ dis,
                                                 const int* __restrict__ nstart,
                                                 const int* __restrict__ ndeg,
                                                 const int* __restrict__ srcs,
                                                 float* __restrict__ out) {
    const int v = (blockIdx.x * 256 + threadIdx.x) >> 4;
    if (v >= NN) return;
    const int f8 = threadIdx.x & 15;
    const uint4* h4 = (const uint4*)hb;

    const float dv = dis[v];
    float4 aL = ((const float4*)b)[f8 * 2];
    float4 aH = ((const float4*)b)[f8 * 2 + 1];
    {
        const float sl = dv * dv;
        uint4 u = h4[(size_t)v * 16 + f8];
        acc8(aL, aH, sl, u);
    }

    const int e0 = nstart[v];
    gather_loop(h4, dis, srcs, e0, e0 + ndeg[v], f8, dv, aL, aH);

    // nontemporal final stores (out is never re-read on device)
    f32x4v vL = {aL.x, aL.y, aL.z, aL.w};
    f32x4v vH = {aH.x, aH.y, aH.z, aH.w};
    f32x4v* o = (f32x4v*)out;
    __builtin_nontemporal_store(vL, &o[(size_t)v * 32 + f8 * 2]);
    __builtin_nontemporal_store(vH, &o[(size_t)v * 32 + f8 * 2 + 1]);
}

// ================= launch =================

extern "C" void kernel_launch(void* const* d_in, const int* in_sizes, int n_in,
                              void* d_out, int out_size, void* d_ws, size_t ws_size,
                              hipStream_t stream) {
    const float* x  = (const float*)d_in[0];
    const int*   ei = (const int*)d_in[1];
    const float* W1 = (const float*)d_in[2];
    const float* b1 = (const float*)d_in[3];
    const float* W2 = (const float*)d_in[4];
    const float* b2 = (const float*)d_in[5];
    float* out = (float*)d_out;

    const int* row = ei;        // source (gather side)
    const int* col = ei + NE;   // target (scatter side)

    // ---- workspace layout (256B-aligned regions) ----
    char* base = (char*)d_ws;
    size_t o = 0;
    auto take = [&](size_t bytes) -> void* {
        void* p = base + o;
        o += (bytes + 255) & ~(size_t)255;
        return p;
    };
    int*   nstart  = (int*)take((size_t)NN * 4);
    int*   ndeg    = (int*)take((size_t)NN * 4);
    int*   bcur    = (int*)take(256 * 4);
    float* dis     = (float*)take((size_t)NN * 4);
    u16*   Wf1     = (u16*)take(16384 * 2);
    u16*   Wf2     = (u16*)take(16384 * 2);
    u16*   hb      = (u16*)take((size_t)NN * FD * 2);   // layer-1 GEMM out
    u16*   hb2     = (u16*)take((size_t)NN * FD * 2);   // layer-2 GEMM out
    int*   srcs    = (int*)take((size_t)NBUK * BCAP * 4);
    u32*   ebuf    = (u32*)take((size_t)NBUK * BCAP * 4);

    // 1. init cursors (tiny)
    k_binit<<<1, 256, 0, stream>>>(bcur);
    // 2. bin edges (391 blocks) + weight pack (8 aux blocks) in one launch
    k_bin<<<NBB + 8, 256, 0, stream>>>(row, col, bcur, ebuf, W1, W2, Wf1, Wf2);
    // 3. mega2: bucket sort (blocks 0..195) || GEMM-1 (blocks 196..)
    k_mega2<<<NBUK + GEMM_BLKS, 256, 0, stream>>>(ebuf, bcur, nstart, ndeg, dis, srcs,
                                                  x, Wf1, hb);
    // 4. fused gather-1 + bias + ReLU + GEMM-2
    k_agg2<<<NGROUP, 256, 0, stream>>>(hb, b1, dis, nstart, ndeg, srcs, Wf2, hb2);
    // 5. gather-2 -> f32 out
    k_agg_f32<<<NGROUP, 256, 0, stream>>>(hb2, b2, dis, nstart, ndeg, srcs, out);
}

// Round 15
// 193.108 us; speedup vs baseline: 1.0609x; 1.0609x over previous
//
#include <hip/hip_runtime.h>

#define NN 100000
#define NE 1600000
#define FD 128
#define NBUK 196            // ceil(NN / 512), bucket = col >> 9
#define BCAP 9216           // fixed slots per bucket (mean 8163, +11 sigma)
#define EPBB 4096           // edges per block in k_bin
#define NBB 391             // ceil(NE / EPBB)
#define NGROUP 6250         // NN/16 row-groups for MFMA gemm
#define GEMM_BLKS 1563      // ceil(NGROUP / 4)

typedef unsigned int  u32;
typedef unsigned short u16;
typedef __bf16 bf16x8 __attribute__((ext_vector_type(8)));
typedef float  f32x4v __attribute__((ext_vector_type(4)));

__device__ __forceinline__ u16 f2bf(float f) {
    u32 u = __float_as_uint(f);
    u32 r = (u + 0x7FFFu + ((u >> 16) & 1u)) >> 16;   // RNE
    return (u16)r;
}

__device__ __forceinline__ void acc2(float& x, float& y, float wt, u32 w) {
    x += wt * __uint_as_float(w << 16);
    y += wt * __uint_as_float(w & 0xffff0000u);
}
__device__ __forceinline__ void acc8(float4& L, float4& H, float wt, uint4 u) {
    acc2(L.x, L.y, wt, u.x); acc2(L.z, L.w, wt, u.y);
    acc2(H.x, H.y, wt, u.z); acc2(H.z, H.w, wt, u.w);
}

// ============ bin edges (blocks 0..NBB-1) + pack W (blocks NBB..) ==============
// B elem = W[q*32 + (l>>4)*8 + j][t*16 + (l&15)]  stored at Wf[((t*4+q)*64+l)*8+j]
__global__ __launch_bounds__(256) void k_bin(const int* __restrict__ row,
                                             const int* __restrict__ col,
                                             int* __restrict__ bcur,
                                             u32* __restrict__ ebuf,
                                             const float* __restrict__ W1,
                                             const float* __restrict__ W2,
                                             u16* __restrict__ Wf1,
                                             u16* __restrict__ Wf2) {
    __shared__ int hist[NBUK];
    const int tid = threadIdx.x;

    if (blockIdx.x >= NBB) {
        // ---- aux blocks: weight pack (8 blocks) ----
        int t2 = (blockIdx.x - NBB) * 256 + tid;   // 0..2047
        if (t2 >= 2048) return;
        int l = t2 & 63;
        int tq = t2 >> 6;
        int q = tq & 3, t = tq >> 2;
        int n = t * 16 + (l & 15);
        int k0 = q * 32 + (l >> 4) * 8;
        u32 p[4], r[4];
        for (int jj = 0; jj < 4; ++jj) {
            u16 lo1 = f2bf(W1[(size_t)(k0 + 2 * jj) * FD + n]);
            u16 hi1 = f2bf(W1[(size_t)(k0 + 2 * jj + 1) * FD + n]);
            p[jj] = (u32)lo1 | ((u32)hi1 << 16);
            u16 lo2 = f2bf(W2[(size_t)(k0 + 2 * jj) * FD + n]);
            u16 hi2 = f2bf(W2[(size_t)(k0 + 2 * jj + 1) * FD + n]);
            r[jj] = (u32)lo2 | ((u32)hi2 << 16);
        }
        *(uint4*)&Wf1[(size_t)t2 * 8] = make_uint4(p[0], p[1], p[2], p[3]);
        *(uint4*)&Wf2[(size_t)t2 * 8] = make_uint4(r[0], r[1], r[2], r[3]);
        return;
    }

    for (int i = tid; i < NBUK; i += 256) hist[i] = 0;
    __syncthreads();
    const int e0 = blockIdx.x * EPBB;
    const int e1 = min(e0 + EPBB, NE);
    for (int e = e0 + tid; e < e1; e += 256)
        atomicAdd(&hist[col[e] >> 9], 1);
    __syncthreads();
    for (int i = tid; i < NBUK; i += 256) {
        int c = hist[i];
        hist[i] = c ? atomicAdd(&bcur[i], c) : 0;
    }
    __syncthreads();
    for (int e = e0 + tid; e < e1; e += 256) {
        int c = col[e];
        int pos = atomicAdd(&hist[c >> 9], 1);
        ebuf[pos] = ((u32)row[e] << 9) | (u32)(c & 511);
    }
}

__global__ void k_binit(int* __restrict__ bcur) {
    int i = threadIdx.x;
    if (i < NBUK) bcur[i] = i * BCAP;
}

// ============ mega2: blocks [0,NBUK) bucket-sort; blocks [NBUK,..) GEMM-1 ======
__global__ __launch_bounds__(256, 4) void k_mega2(const u32* __restrict__ ebuf,
                                                  const int* __restrict__ bcur,
                                                  int* __restrict__ nstart,
                                                  int* __restrict__ ndeg,
                                                  float* __restrict__ dis,
                                                  int* __restrict__ srcs,
                                                  const float* __restrict__ x,
                                                  const u16* __restrict__ Wf1,
                                                  u16* __restrict__ hb) {
    __shared__ u16 smem[16384];     // 32 KB union: bucket uses 3 KB; gemm uses all
    const int tid = threadIdx.x;

    if (blockIdx.x < NBUK) {
        // ---- per-bucket counting sort -> CSC ----
        int* lcnt = (int*)smem;             // 512 ints
        int* s = lcnt + 512;                // 256 ints
        const int b = blockIdx.x;
        const int base = b * BCAP;
        const int end = bcur[b];            // base + actual count

        lcnt[tid] = 0; lcnt[tid + 256] = 0;
        __syncthreads();
        for (int i = base + tid; i < end; i += 256)
            atomicAdd(&lcnt[ebuf[i] & 511], 1);
        __syncthreads();

        const int c0 = lcnt[tid * 2], c1 = lcnt[tid * 2 + 1];
        s[tid] = c0 + c1;
        __syncthreads();
        for (int off = 1; off < 256; off <<= 1) {
            int t = 0;
            if (tid >= off) t = s[tid - off];
            __syncthreads();
            if (tid >= off) s[tid] += t;
            __syncthreads();
        }
        const int excl = (tid == 0) ? 0 : s[tid - 1];
        __syncthreads();
        lcnt[tid * 2] = excl;
        lcnt[tid * 2 + 1] = excl + c0;

        const int v0 = b * 512 + tid * 2;
        if (v0 < NN) {
            nstart[v0] = base + excl;
            ndeg[v0] = c0;
            dis[v0] = rsqrtf((float)c0 + 1.0f);
        }
        if (v0 + 1 < NN) {
            nstart[v0 + 1] = base + excl + c0;
            ndeg[v0 + 1] = c1;
            dis[v0 + 1] = rsqrtf((float)c1 + 1.0f);
        }
        __syncthreads();

        for (int i = base + tid; i < end; i += 256) {
            u32 p = ebuf[i];
            int pos = atomicAdd(&lcnt[p & 511], 1);
            srcs[base + pos] = (int)(p >> 9);
        }
        return;
    }

    // ---- GEMM-1: hb[r][f] = bf16( sum_k bf16(x[r][k]) * W1[k][f] ) ----
    {
        const uint4* s4 = (const uint4*)Wf1;
        uint4* d = (uint4*)smem;
#pragma unroll
        for (int i = 0; i < 8; ++i) d[tid + 256 * i] = s4[tid + 256 * i];
    }
    __syncthreads();

    const int wave = tid >> 6, lane = tid & 63;
    const int gid = (blockIdx.x - NBUK) * 4 + wave;
    if (gid >= NGROUP) return;
    const int row0 = gid * 16;
    const int lr = lane & 15;
    const int lh = lane >> 4;

    f32x4v acc[8];
#pragma unroll
    for (int t = 0; t < 8; ++t) { f32x4v z = {0.f, 0.f, 0.f, 0.f}; acc[t] = z; }

#pragma unroll
    for (int q = 0; q < 4; ++q) {
        const float* arow = x + (size_t)(row0 + lr) * FD + lh * 8 + q * 32;
        float4 f0 = *(const float4*)(arow);
        float4 f1 = *(const float4*)(arow + 4);
        union { bf16x8 v; u16 s[8]; } ua;
        ua.s[0] = f2bf(f0.x); ua.s[1] = f2bf(f0.y);
        ua.s[2] = f2bf(f0.z); ua.s[3] = f2bf(f0.w);
        ua.s[4] = f2bf(f1.x); ua.s[5] = f2bf(f1.y);
        ua.s[6] = f2bf(f1.z); ua.s[7] = f2bf(f1.w);
        bf16x8 a = ua.v;
#pragma unroll
        for (int t = 0; t < 8; ++t) {
            bf16x8 bfr = *(const bf16x8*)(&smem[(size_t)(t * 4 + q) * 512 + lane * 8]);
            acc[t] = __builtin_amdgcn_mfma_f32_16x16x32_bf16(a, bfr, acc[t], 0, 0, 0);
        }
    }
#pragma unroll
    for (int t = 0; t < 8; ++t) {
#pragma unroll
        for (int j = 0; j < 4; ++j) {
            const int r = row0 + lh * 4 + j;
            hb[(size_t)r * FD + t * 16 + lr] = f2bf(acc[t][j]);
        }
    }
}

// 4-deep gather core (VGPR-lean: occupancy beats unroll for random gathers)
__device__ __forceinline__ void gather_loop(const uint4* __restrict__ h4,
                                            const float* __restrict__ dis,
                                            const int* __restrict__ srcs,
                                            int e, int end, int f8, float dv,
                                            float4& aL, float4& aH) {
    for (; e + 3 < end; e += 4) {
        const int s0 = srcs[e], s1 = srcs[e + 1], s2 = srcs[e + 2], s3 = srcs[e + 3];
        const float w0 = dv * dis[s0];
        const float w1 = dv * dis[s1];
        const float w2 = dv * dis[s2];
        const float w3 = dv * dis[s3];
        const uint4 u0 = h4[(size_t)s0 * 16 + f8];
        const uint4 u1 = h4[(size_t)s1 * 16 + f8];
        const uint4 u2 = h4[(size_t)s2 * 16 + f8];
        const uint4 u3 = h4[(size_t)s3 * 16 + f8];
        acc8(aL, aH, w0, u0); acc8(aL, aH, w1, u1);
        acc8(aL, aH, w2, u2); acc8(aL, aH, w3, u3);
    }
    for (; e < end; ++e) {
        const int s0 = srcs[e];
        const float w0 = dv * dis[s0];
        const uint4 u0 = h4[(size_t)s0 * 16 + f8];
        acc8(aL, aH, w0, u0);
    }
}

// ============ fused: gather-1 + bias + ReLU + GEMM-2 -> hb2 (bf16) =============
__global__ __launch_bounds__(256) void k_agg2(const u16* __restrict__ hb,
                                              const float* __restrict__ b1,
                                              const float* __restrict__ dis,
                                              const int* __restrict__ nstart,
                                              const int* __restrict__ ndeg,
                                              const int* __restrict__ srcs,
                                              const u16* __restrict__ Wf2,
                                              u16* __restrict__ hb2) {
    __shared__ u16 tile[16 * 136];      // 4352 B
    const int tid = threadIdx.x;
    const int nl = tid >> 4;            // node-local 0..15
    const int f8 = tid & 15;            // 8-feature slice
    const int v = blockIdx.x * 16 + nl; // always < NN (6250*16 = NN)
    const uint4* h4 = (const uint4*)hb;

    const float dv = dis[v];
    float4 aL = ((const float4*)b1)[f8 * 2];
    float4 aH = ((const float4*)b1)[f8 * 2 + 1];
    {
        const float sl = dv * dv;
        uint4 u = h4[(size_t)v * 16 + f8];
        acc8(aL, aH, sl, u);
    }

    const int e0 = nstart[v];
    gather_loop(h4, dis, srcs, e0, e0 + ndeg[v], f8, dv, aL, aH);

    // ReLU + bf16 pack -> LDS tile
    {
        uint4 p;
        p.x = (u32)f2bf(fmaxf(aL.x, 0.f)) | ((u32)f2bf(fmaxf(aL.y, 0.f)) << 16);
        p.y = (u32)f2bf(fmaxf(aL.z, 0.f)) | ((u32)f2bf(fmaxf(aL.w, 0.f)) << 16);
        p.z = (u32)f2bf(fmaxf(aH.x, 0.f)) | ((u32)f2bf(fmaxf(aH.y, 0.f)) << 16);
        p.w = (u32)f2bf(fmaxf(aH.z, 0.f)) | ((u32)f2bf(fmaxf(aH.w, 0.f)) << 16);
        *(uint4*)&tile[nl * 136 + f8 * 8] = p;
    }
    __syncthreads();

    // GEMM-2 on the 16-row tile: wave w owns n-tiles 2w, 2w+1
    const int wave = tid >> 6, lane = tid & 63;
    const int lr = lane & 15;
    const int lh = lane >> 4;
    f32x4v a0 = {0.f, 0.f, 0.f, 0.f}, a1 = {0.f, 0.f, 0.f, 0.f};
#pragma unroll
    for (int q = 0; q < 4; ++q) {
        bf16x8 a = *(const bf16x8*)&tile[lr * 136 + q * 32 + lh * 8];
        bf16x8 bb0 = *(const bf16x8*)&Wf2[(size_t)((2 * wave) * 4 + q) * 512 + lane * 8];
        bf16x8 bb1 = *(const bf16x8*)&Wf2[(size_t)((2 * wave + 1) * 4 + q) * 512 + lane * 8];
        a0 = __builtin_amdgcn_mfma_f32_16x16x32_bf16(a, bb0, a0, 0, 0, 0);
        a1 = __builtin_amdgcn_mfma_f32_16x16x32_bf16(a, bb1, a1, 0, 0, 0);
    }
    const int row0 = blockIdx.x * 16;
#pragma unroll
    for (int j = 0; j < 4; ++j) {
        const int r = row0 + lh * 4 + j;
        hb2[(size_t)r * FD + (2 * wave) * 16 + lr] = f2bf(a0[j]);
        hb2[(size_t)r * FD + (2 * wave + 1) * 16 + lr] = f2bf(a1[j]);
    }
}

// ============ gather-2: out f32 = b2 + dv^2*h2[v] + sum w*h2[src] ==============
__global__ __launch_bounds__(256) void k_agg_f32(const u16* __restrict__ hb,
                                                 const float* __restrict__ b,
                                                 const float* __restrict__ dis,
                                                 const int* __restrict__ nstart,
                                                 const int* __restrict__ ndeg,
                                                 const int* __restrict__ srcs,
                                                 float* __restrict__ out) {
    const int v = (blockIdx.x * 256 + threadIdx.x) >> 4;
    if (v >= NN) return;
    const int f8 = threadIdx.x & 15;
    const uint4* h4 = (const uint4*)hb;

    const float dv = dis[v];
    float4 aL = ((const float4*)b)[f8 * 2];
    float4 aH = ((const float4*)b)[f8 * 2 + 1];
    {
        const float sl = dv * dv;
        uint4 u = h4[(size_t)v * 16 + f8];
        acc8(aL, aH, sl, u);
    }

    const int e0 = nstart[v];
    gather_loop(h4, dis, srcs, e0, e0 + ndeg[v], f8, dv, aL, aH);

    // nontemporal final stores (out is never re-read on device)
    f32x4v vL = {aL.x, aL.y, aL.z, aL.w};
    f32x4v vH = {aH.x, aH.y, aH.z, aH.w};
    f32x4v* o = (f32x4v*)out;
    __builtin_nontemporal_store(vL, &o[(size_t)v * 32 + f8 * 2]);
    __builtin_nontemporal_store(vH, &o[(size_t)v * 32 + f8 * 2 + 1]);
}

// ================= launch =================

extern "C" void kernel_launch(void* const* d_in, const int* in_sizes, int n_in,
                              void* d_out, int out_size, void* d_ws, size_t ws_size,
                              hipStream_t stream) {
    const float* x  = (const float*)d_in[0];
    const int*   ei = (const int*)d_in[1];
    const float* W1 = (const float*)d_in[2];
    const float* b1 = (const float*)d_in[3];
    const float* W2 = (const float*)d_in[4];
    const float* b2 = (const float*)d_in[5];
    float* out = (float*)d_out;

    const int* row = ei;        // source (gather side)
    const int* col = ei + NE;   // target (scatter side)

    // ---- workspace layout (256B-aligned regions) ----
    char* base = (char*)d_ws;
    size_t o = 0;
    auto take = [&](size_t bytes) -> void* {
        void* p = base + o;
        o += (bytes + 255) & ~(size_t)255;
        return p;
    };
    int*   nstart  = (int*)take((size_t)NN * 4);
    int*   ndeg    = (int*)take((size_t)NN * 4);
    int*   bcur    = (int*)take(256 * 4);
    float* dis     = (float*)take((size_t)NN * 4);
    u16*   Wf1     = (u16*)take(16384 * 2);
    u16*   Wf2     = (u16*)take(16384 * 2);
    u16*   hb      = (u16*)take((size_t)NN * FD * 2);   // layer-1 GEMM out
    u16*   hb2     = (u16*)take((size_t)NN * FD * 2);   // layer-2 GEMM out
    int*   srcs    = (int*)take((size_t)NBUK * BCAP * 4);
    u32*   ebuf    = (u32*)take((size_t)NBUK * BCAP * 4);

    // 1. init cursors (tiny)
    k_binit<<<1, 256, 0, stream>>>(bcur);
    // 2. bin edges (391 blocks) + weight pack (8 aux blocks) in one launch
    k_bin<<<NBB + 8, 256, 0, stream>>>(row, col, bcur, ebuf, W1, W2, Wf1, Wf2);
    // 3. mega2: bucket sort (blocks 0..195) || GEMM-1 (blocks 196..)
    k_mega2<<<NBUK + GEMM_BLKS, 256, 0, stream>>>(ebuf, bcur, nstart, ndeg, dis, srcs,
                                                  x, Wf1, hb);
    // 4. fused gather-1 + bias + ReLU + GEMM-2
    k_agg2<<<NGROUP, 256, 0, stream>>>(hb, b1, dis, nstart, ndeg, srcs, Wf2, hb2);
    // 5. gather-2 -> f32 out
    k_agg_f32<<<NGROUP, 256, 0, stream>>>(hb2, b2, dis, nstart, ndeg, srcs, out);
}